// Round 1
// baseline (542.428 us; speedup 1.0000x reference)
//
#include <hip/hip_runtime.h>
#include <hip/hip_bf16.h>

typedef __attribute__((ext_vector_type(8))) short bf16x8;
typedef __attribute__((ext_vector_type(4))) float f32x4;

static __device__ __forceinline__ unsigned short f2bf(float f){
  __hip_bfloat16 h = __float2bfloat16(f);
  return *reinterpret_cast<unsigned short*>(&h);
}

static __device__ __forceinline__ void gload16(const void* g, void* l){
  __builtin_amdgcn_global_load_lds((__attribute__((address_space(1))) void*)g,
                                   (__attribute__((address_space(3))) void*)l, 16, 0, 0);
}

static __device__ __forceinline__ f32x4 mfma16(bf16x8 a, bf16x8 b, f32x4 c){
  return __builtin_amdgcn_mfma_f32_16x16x32_bf16(a, b, c, 0, 0, 0);
}

// ---------------- f32 -> bf16 convert ----------------
__global__ __launch_bounds__(256) void k_cvt(const float* __restrict__ in,
                                             unsigned short* __restrict__ out, int n4){
  int i = blockIdx.x*256 + threadIdx.x;
  if (i >= n4) return;
  const float4 v = reinterpret_cast<const float4*>(in)[i];
  ushort4 o;
  o.x = f2bf(v.x); o.y = f2bf(v.y); o.z = f2bf(v.z); o.w = f2bf(v.w);
  reinterpret_cast<ushort4*>(out)[i] = o;
}

// ---------------- generic 128x128 BT GEMM, K=512 ----------------
// C[m,n] = epi( sum_k A[m,k]*W[n,k] + bias[n] )
// EPI 0: write bf16 to concat layout [b,h,pos, hlf*64+d] (128 cols, XOR-swizzled rows), scaled by fac
// EPI 1: write bf16 to V^T layout [b,h,d,pos]
// EPI 2: write f32 to out[m*512+n]
template<int EPI>
__global__ __launch_bounds__(256) void k_gemm(const unsigned short* __restrict__ A,
                                              const unsigned short* __restrict__ W,
                                              const float* __restrict__ bias,
                                              void* __restrict__ out,
                                              int Lshift, int hlf, int facmode,
                                              const float* __restrict__ alphap){
  __shared__ unsigned short As[128*32];
  __shared__ unsigned short Bs[128*32];
  const int t = threadIdx.x, l = t&63, w = t>>6;
  const int m0 = blockIdx.x*128, n0 = blockIdx.y*128;
  const int wm = w>>1, wn = w&1;
  f32x4 acc[4][4] = {};
  const char* Ab = (const char*)A + (size_t)m0*1024;
  const char* Wb = (const char*)W + (size_t)n0*1024;
  char* AsB = (char*)As; char* BsB = (char*)Bs;
  const int lofs = w*1024;
  const int grow = w*16 + (l>>2);     // row within 64-row issue
  const int gcol = (l&3)*16;          // byte within 64B k-slice

  for (int kt=0; kt<16; ++kt){
    __syncthreads();
    const int kb = kt*64;
    for (int i=0;i<2;++i){
      gload16(Ab + (size_t)(i*64 + grow)*1024 + kb + gcol, AsB + i*4096 + lofs);
      gload16(Wb + (size_t)(i*64 + grow)*1024 + kb + gcol, BsB + i*4096 + lofs);
    }
    __syncthreads();
    bf16x8 a[4], b[4];
    for (int i=0;i<4;++i){
      a[i] = *(const bf16x8*)(AsB + (wm*64 + i*16 + (l&15))*64 + (l>>4)*16);
      b[i] = *(const bf16x8*)(BsB + (wn*64 + i*16 + (l&15))*64 + (l>>4)*16);
    }
    for (int i=0;i<4;++i)
      for (int j=0;j<4;++j)
        acc[i][j] = mfma16(a[i], b[j], acc[i][j]);
  }

  float fac = 1.f;
  if (EPI==0 && facmode != 2){
    float al = alphap[0];
    float sg = 1.f/(1.f + __expf(-al));
    fac = (facmode==0 ? sg : (1.f-sg)) * 0.125f;
  }
  const int Lseq = 1 << Lshift;
  for (int i=0;i<4;++i){
    for (int j=0;j<4;++j){
      const int nn = n0 + wn*64 + j*16 + (l&15);
      const float bv = bias[nn];
      for (int r=0;r<4;++r){
        const int mm = m0 + wm*64 + i*16 + (l>>4)*4 + r;
        float v = acc[i][j][r] + bv;
        if (EPI==0){
          v *= fac;
          int bb = mm >> Lshift, pos = mm & (Lseq-1);
          int h = nn>>6, d = nn&63;
          size_t rowoff = ((size_t)(bb*8+h)*Lseq + pos)*256;
          int colb = (((hlf<<6)+d)*2) ^ ((pos&7)<<4);
          *(unsigned short*)((char*)out + rowoff + colb) = f2bf(v);
        } else if (EPI==1){
          int bb = mm >> Lshift, pos = mm & (Lseq-1);
          int h = nn>>6, d = nn&63;
          ((unsigned short*)out)[ ((size_t)(bb*8+h)*64 + d)*Lseq + pos ] = f2bf(v);
        } else {
          ((float*)out)[ (size_t)mm*512 + nn ] = v;
        }
      }
    }
  }
}

// ---------------- fused logits + softmax ----------------
// block = (bh, qtile of 128). Dmat tile resident in LDS; two passes over 8 p-tiles:
// pass0 accumulates row sums of exp(logit); pass1 recomputes and writes normalized attn (f32).
__global__ __launch_bounds__(256) void k_attn(const unsigned short* __restrict__ Dmat,
                                              const unsigned short* __restrict__ Pmat,
                                              float* __restrict__ attn_out){
  const int bh = blockIdx.x, qt = blockIdx.y;
  __shared__ unsigned short Dm[128*128];
  __shared__ unsigned short Pm[128*128];
  __shared__ float rinv[128];
  const int t = threadIdx.x, l = t&63, w = t>>6;
  const char* dsrc = (const char*)Dmat + ((size_t)bh*256 + qt*128)*256;
  const char* psrcB = (const char*)Pmat + (size_t)bh*1024*256;
  char* DmB = (char*)Dm; char* PmB = (char*)Pm;
  const int lofs = w*1024;

  for (int i=0;i<8;++i)
    gload16(dsrc + i*4096 + lofs + l*16, DmB + i*4096 + lofs);

  float rs[2][4] = {{0,0,0,0},{0,0,0,0}};
  for (int pass=0; pass<2; ++pass){
    for (int pt=0; pt<8; ++pt){
      __syncthreads();
      const char* ps = psrcB + pt*32768;
      for (int i=0;i<8;++i)
        gload16(ps + i*4096 + lofs + l*16, PmB + i*4096 + lofs);
      __syncthreads();
      f32x4 acc[2][8] = {};
      for (int kt=0;kt<4;++kt){
        bf16x8 a[2];
        for (int fm=0;fm<2;++fm){
          int row = w*32 + fm*16 + (l&15);
          int byteo = (kt*64 + (l>>4)*16) ^ ((row&7)<<4);
          a[fm] = *(const bf16x8*)(DmB + row*256 + byteo);
        }
        for (int fn=0;fn<8;++fn){
          int row = fn*16 + (l&15);
          int byteo = (kt*64 + (l>>4)*16) ^ ((row&7)<<4);
          bf16x8 b = *(const bf16x8*)(PmB + row*256 + byteo);
          acc[0][fn] = mfma16(a[0], b, acc[0][fn]);
          acc[1][fn] = mfma16(a[1], b, acc[1][fn]);
        }
      }
      if (pass==0){
        for (int fm=0;fm<2;++fm)
          for (int fn=0;fn<8;++fn)
            for (int r=0;r<4;++r)
              rs[fm][r] += __expf(acc[fm][fn][r]);
      } else {
        for (int fm=0;fm<2;++fm){
          for (int r=0;r<4;++r){
            const int row = w*32 + fm*16 + (l>>4)*4 + r;
            const float ri = rinv[row];
            float* op = attn_out + ((size_t)bh*256 + qt*128 + row)*1024 + pt*128 + (l&15);
            for (int fn=0;fn<8;++fn)
              op[fn*16] = __expf(acc[fm][fn][r]) * ri;
          }
        }
      }
    }
    if (pass==0){
      for (int m=1;m<16;m<<=1)
        for (int fm=0;fm<2;++fm)
          for (int r=0;r<4;++r)
            rs[fm][r] += __shfl_xor(rs[fm][r], m, 64);
      __syncthreads();
      if ((l&15)==0){
        for (int fm=0;fm<2;++fm)
          for (int r=0;r<4;++r)
            rinv[w*32 + fm*16 + (l>>4)*4 + r] = 1.f/rs[fm][r];
      }
      __syncthreads();
    }
  }
}

// ---------------- ctx_d = attn @ Vp : per (bh, 128-q tile), N=64, K=1024 ----------------
__global__ __launch_bounds__(256) void k_ctxd(const float* __restrict__ attn,
                                              const unsigned short* __restrict__ Vpt,
                                              unsigned short* __restrict__ ctxd){
  const int bh = blockIdx.x, mt = blockIdx.y;
  const int b = bh>>3, h = bh&7;
  __shared__ unsigned short As[128*40];
  __shared__ unsigned short Bs[64*40];
  const int t = threadIdx.x, l = t&63, w = t>>6;
  f32x4 acc[2][4] = {};
  const float* abase = attn + ((size_t)bh*256 + mt*128)*1024;
  const unsigned short* vbase = Vpt + (size_t)bh*65536;
  for (int kt=0; kt<32; ++kt){
    __syncthreads();
    for (int i=0;i<4;++i){
      int id = t + i*256;
      int row = id>>3, c4 = id&7;
      float4 v = *(const float4*)(abase + (size_t)row*1024 + kt*32 + c4*4);
      ushort4 o = { f2bf(v.x), f2bf(v.y), f2bf(v.z), f2bf(v.w) };
      *(ushort4*)(As + row*40 + c4*4) = o;
    }
    for (int i=0;i<2;++i){
      int id = t + i*256;
      int row = id>>3, c4 = id&7;
      *(ushort4*)(Bs + row*40 + c4*4) = *(const ushort4*)(vbase + (size_t)row*1024 + kt*32 + c4*4);
    }
    __syncthreads();
    bf16x8 a[2], bb[4];
    for (int fm=0;fm<2;++fm)
      a[fm] = *(const bf16x8*)(As + (w*32 + fm*16 + (l&15))*40 + (l>>4)*8);
    for (int fn=0;fn<4;++fn)
      bb[fn] = *(const bf16x8*)(Bs + (fn*16 + (l&15))*40 + (l>>4)*8);
    for (int fm=0;fm<2;++fm)
      for (int fn=0;fn<4;++fn)
        acc[fm][fn] = mfma16(a[fm], bb[fn], acc[fm][fn]);
  }
  for (int fm=0;fm<2;++fm)
    for (int fn=0;fn<4;++fn)
      for (int r=0;r<4;++r){
        int row = w*32 + fm*16 + (l>>4)*4 + r;
        int col = fn*16 + (l&15);
        ctxd[ ((size_t)b*256 + mt*128 + row)*512 + h*64 + col ] = f2bf(acc[fm][fn][r]);
      }
}

// ---------------- ctx_p = attn^T @ Vd : per (bh, 128-p tile), N=64, K=256 ----------------
__global__ __launch_bounds__(256) void k_ctxp(const float* __restrict__ attn,
                                              const unsigned short* __restrict__ Vdt,
                                              unsigned short* __restrict__ ctxp){
  const int bh = blockIdx.x, mt = blockIdx.y;
  const int b = bh>>3, h = bh&7;
  __shared__ unsigned short As[128*40];
  __shared__ unsigned short Bs[64*40];
  const int t = threadIdx.x, l = t&63, w = t>>6;
  f32x4 acc[2][4] = {};
  const float* abase = attn + (size_t)bh*256*1024 + mt*128;
  const unsigned short* vbase = Vdt + (size_t)bh*16384;
  for (int kt=0; kt<8; ++kt){
    __syncthreads();
    for (int i=0;i<4;++i){
      int id = t + i*256;
      int ql = id>>5, p4 = id&31;
      float4 v = *(const float4*)(abase + (size_t)(kt*32 + ql)*1024 + p4*4);
      As[(p4*4+0)*40 + ql] = f2bf(v.x);
      As[(p4*4+1)*40 + ql] = f2bf(v.y);
      As[(p4*4+2)*40 + ql] = f2bf(v.z);
      As[(p4*4+3)*40 + ql] = f2bf(v.w);
    }
    for (int i=0;i<2;++i){
      int id = t + i*256;
      int row = id>>3, c4 = id&7;
      *(ushort4*)(Bs + row*40 + c4*4) = *(const ushort4*)(vbase + (size_t)row*256 + kt*32 + c4*4);
    }
    __syncthreads();
    bf16x8 a[2], bb[4];
    for (int fm=0;fm<2;++fm)
      a[fm] = *(const bf16x8*)(As + (w*32 + fm*16 + (l&15))*40 + (l>>4)*8);
    for (int fn=0;fn<4;++fn)
      bb[fn] = *(const bf16x8*)(Bs + (fn*16 + (l&15))*40 + (l>>4)*8);
    for (int fm=0;fm<2;++fm)
      for (int fn=0;fn<4;++fn)
        acc[fm][fn] = mfma16(a[fm], bb[fn], acc[fm][fn]);
  }
  for (int fm=0;fm<2;++fm)
    for (int fn=0;fn<4;++fn)
      for (int r=0;r<4;++r){
        int row = w*32 + fm*16 + (l>>4)*4 + r;
        int col = fn*16 + (l&15);
        ctxp[ ((size_t)b*1024 + mt*128 + row)*512 + h*64 + col ] = f2bf(acc[fm][fn][r]);
      }
}

extern "C" void kernel_launch(void* const* d_in, const int* in_sizes, int n_in,
                              void* d_out, int out_size, void* d_ws, size_t ws_size,
                              hipStream_t stream){
  const float* drug    = (const float*)d_in[0];
  const float* protein = (const float*)d_in[1];
  const float* Wqd=(const float*)d_in[2];  const float* bqd=(const float*)d_in[3];
  const float* Wkp=(const float*)d_in[4];  const float* bkp=(const float*)d_in[5];
  const float* Wvp=(const float*)d_in[6];  const float* bvp=(const float*)d_in[7];
  const float* Wqp=(const float*)d_in[8];  const float* bqp=(const float*)d_in[9];
  const float* Wkd=(const float*)d_in[10]; const float* bkd=(const float*)d_in[11];
  const float* Wvd=(const float*)d_in[12]; const float* bvd=(const float*)d_in[13];
  const float* alpha=(const float*)d_in[14];
  const float* Wod=(const float*)d_in[15]; const float* bod=(const float*)d_in[16];
  const float* Wop=(const float*)d_in[17]; const float* bop=(const float*)d_in[18];

  char* ws = (char*)d_ws;
  unsigned short* Xd  = (unsigned short*)(ws + 0);          // 8192x512 bf16
  unsigned short* Xp  = (unsigned short*)(ws + 8388608);    // 32768x512 bf16
  unsigned short* Wb  = (unsigned short*)(ws + 41943040);   // 8 x 512x512 bf16
  unsigned short* Dm  = (unsigned short*)(ws + 46137344);   // [bh][256][128] bf16, swizzled
  unsigned short* Pm  = (unsigned short*)(ws + 62914560);   // [bh][1024][128] bf16, swizzled
  unsigned short* Vpt = (unsigned short*)(ws + 130023424);  // [bh][64][1024] bf16
  unsigned short* Vdt = (unsigned short*)(ws + 163577856);  // [bh][64][256] bf16
  unsigned short* Cd  = (unsigned short*)(ws + 0);          // overlay on Xd (dead after projections)
  unsigned short* Cp  = (unsigned short*)(ws + 8388608);    // overlay on Xp

  float* attn = (float*)d_out;
  float* outd = (float*)d_out + 67108864;
  float* outp = (float*)d_out + 71303168;

  // f32 -> bf16 conversions
  k_cvt<<<4096, 256, 0, stream>>>(drug,    Xd, 1048576);
  k_cvt<<<16384,256, 0, stream>>>(protein, Xp, 4194304);
  const float* wsrc[8] = {Wqd, Wkp, Wvp, Wqp, Wkd, Wvd, Wod, Wop};
  for (int i=0;i<8;++i)
    k_cvt<<<256, 256, 0, stream>>>(wsrc[i], Wb + i*262144, 65536);

  // projections: Dmat=[a*s*Qd | (1-a)*s*Kd], Pmat=[Kp | Qp], Vp^T, Vd^T
  k_gemm<0><<<dim3(64, 4),  256, 0, stream>>>(Xd, Wb+0*262144, bqd, Dm,  8,  0, 0, alpha);
  k_gemm<0><<<dim3(64, 4),  256, 0, stream>>>(Xd, Wb+4*262144, bkd, Dm,  8,  1, 1, alpha);
  k_gemm<0><<<dim3(256,4),  256, 0, stream>>>(Xp, Wb+1*262144, bkp, Pm,  10, 0, 2, alpha);
  k_gemm<0><<<dim3(256,4),  256, 0, stream>>>(Xp, Wb+3*262144, bqp, Pm,  10, 1, 2, alpha);
  k_gemm<1><<<dim3(256,4),  256, 0, stream>>>(Xp, Wb+2*262144, bvp, Vpt, 10, 0, 2, alpha);
  k_gemm<1><<<dim3(64, 4),  256, 0, stream>>>(Xd, Wb+5*262144, bvd, Vdt, 8,  0, 2, alpha);

  // fused logits + softmax -> attn (f32, output 0)
  k_attn<<<dim3(256,2), 256, 0, stream>>>(Dm, Pm, attn);

  // context accumulations (read f32 attn from d_out)
  k_ctxd<<<dim3(256,2), 256, 0, stream>>>(attn, Vpt, Cd);
  k_ctxp<<<dim3(256,8), 256, 0, stream>>>(attn, Vdt, Cp);

  // output projections (f32 outputs)
  k_gemm<2><<<dim3(64, 4), 256, 0, stream>>>(Cd, Wb+6*262144, bod, outd, 8,  0, 2, alpha);
  k_gemm<2><<<dim3(256,4), 256, 0, stream>>>(Cp, Wb+7*262144, bop, outp, 10, 0, 2, alpha);
}

// Round 2
// 427.245 us; speedup vs baseline: 1.2696x; 1.2696x over previous
//
#include <hip/hip_runtime.h>
#include <hip/hip_bf16.h>

typedef __attribute__((ext_vector_type(8))) short bf16x8;
typedef __attribute__((ext_vector_type(4))) float f32x4;

static __device__ __forceinline__ unsigned short f2bf(float f){
  __hip_bfloat16 h = __float2bfloat16(f);
  return *reinterpret_cast<unsigned short*>(&h);
}
static __device__ __forceinline__ float bf2f(unsigned short u){
  unsigned int x = ((unsigned int)u) << 16;
  return *reinterpret_cast<float*>(&x);
}
static __device__ __forceinline__ void gload16(const void* g, void* l){
  __builtin_amdgcn_global_load_lds((__attribute__((address_space(1))) void*)g,
                                   (__attribute__((address_space(3))) void*)l, 16, 0, 0);
}
static __device__ __forceinline__ f32x4 mfma16(bf16x8 a, bf16x8 b, f32x4 c){
  return __builtin_amdgcn_mfma_f32_16x16x32_bf16(a, b, c, 0, 0, 0);
}

// ---------------- f32 -> bf16 convert ----------------
__global__ __launch_bounds__(256) void k_cvt(const float* __restrict__ in,
                                             unsigned short* __restrict__ out, int n4){
  int i = blockIdx.x*256 + threadIdx.x;
  if (i >= n4) return;
  const float4 v = reinterpret_cast<const float4*>(in)[i];
  ushort4 o;
  o.x = f2bf(v.x); o.y = f2bf(v.y); o.z = f2bf(v.z); o.w = f2bf(v.w);
  reinterpret_cast<ushort4*>(out)[i] = o;
}

struct W8 { const float* p[8]; };
__global__ __launch_bounds__(256) void k_cvtw(W8 ws, unsigned short* __restrict__ out){
  int w = blockIdx.x >> 8;
  int i = (blockIdx.x & 255)*256 + threadIdx.x;   // 0..65535 float4s
  const float4 v = reinterpret_cast<const float4*>(ws.p[w])[i];
  ushort4 o;
  o.x = f2bf(v.x); o.y = f2bf(v.y); o.z = f2bf(v.z); o.w = f2bf(v.w);
  reinterpret_cast<ushort4*>(out + (size_t)w*262144)[i] = o;
}

// ---------------- fused 3-way projection GEMM (N=1536, K=512, BT) ----------------
// SIDE 0 = drug (L=256, Dm halves scaled by a*s/(1-a)*s, V->Vdt linear)
// SIDE 1 = protein (L=1024, Pm halves unscaled, V->Vpt swizzled)
template<int SIDE>
__global__ __launch_bounds__(256) void k_proj(const unsigned short* __restrict__ A,
                                              const unsigned short* __restrict__ W3,
                                              const float* __restrict__ b0,
                                              const float* __restrict__ b1,
                                              const float* __restrict__ b2,
                                              unsigned short* __restrict__ o01,
                                              unsigned short* __restrict__ oV,
                                              const float* __restrict__ alphap){
  constexpr int LSH = SIDE ? 10 : 8;
  constexpr int MPX = SIDE ? 32 : 8;     // m-tiles per XCD
  __shared__ unsigned short As[128*32];
  __shared__ unsigned short Bs[128*32];
  const int id = blockIdx.x, xcd = id & 7, j = id >> 3;
  const int m0 = (xcd*MPX + j/12) * 128;
  const int n0 = (j % 12) * 128;
  const int t = threadIdx.x, l = t&63, w = t>>6;
  const int wm = w>>1, wn = w&1;
  f32x4 acc[4][4] = {};
  const char* Ab = (const char*)A + (size_t)m0*1024;
  const char* Wb = (const char*)W3 + (size_t)n0*1024;
  char* AsB = (char*)As; char* BsB = (char*)Bs;
  const int lofs = w*1024;
  const int grow = w*16 + (l>>2);
  const int gcol = (l&3)*16;

  for (int kt=0; kt<16; ++kt){
    __syncthreads();
    const int kb = kt*64;
    for (int i=0;i<2;++i){
      gload16(Ab + (size_t)(i*64 + grow)*1024 + kb + gcol, AsB + i*4096 + lofs);
      gload16(Wb + (size_t)(i*64 + grow)*1024 + kb + gcol, BsB + i*4096 + lofs);
    }
    __syncthreads();
    bf16x8 a[4], b[4];
    for (int i=0;i<4;++i){
      a[i] = *(const bf16x8*)(AsB + (wm*64 + i*16 + (l&15))*64 + (l>>4)*16);
      b[i] = *(const bf16x8*)(BsB + (wn*64 + i*16 + (l&15))*64 + (l>>4)*16);
    }
    for (int i=0;i<4;++i)
      for (int jj=0;jj<4;++jj)
        acc[i][jj] = mfma16(a[i], b[jj], acc[i][jj]);
  }

  const float al = alphap[0];
  const float sg = 1.f/(1.f + __expf(-al));
  const int Lseq = 1 << LSH;
  for (int i=0;i<4;++i){
    for (int jj=0;jj<4;++jj){
      const int nn = n0 + wn*64 + jj*16 + (l&15);
      const int g = nn>>9, c = nn&511, h = c>>6, d = c&63;
      const float bv = (g==0 ? b0 : (g==1 ? b1 : b2))[c];
      for (int r=0;r<4;++r){
        const int mm = m0 + wm*64 + i*16 + (l>>4)*4 + r;
        float v = acc[i][jj][r] + bv;
        const int bb = mm >> LSH, pos = mm & (Lseq-1);
        if (g < 2){
          if (SIDE==0) v *= (g==0 ? sg : (1.f-sg)) * 0.125f;
          const int c2 = g*64 + d;
          *(unsigned short*)((char*)o01 + ((size_t)(bb*8+h)*Lseq + pos)*256
                             + ((c2*2) ^ ((pos&15)<<4))) = f2bf(v);
        } else {
          if (SIDE==1)
            *(unsigned short*)((char*)oV + ((size_t)(bb*8+h)*64 + d)*2048
                               + ((pos*2) ^ ((d&15)<<4))) = f2bf(v);
          else
            oV[ ((size_t)(bb*8+h)*64 + d)*256 + pos ] = f2bf(v);
        }
      }
    }
  }
}

// ---------------- output projection GEMM (N=512, K=512, f32 out) ----------------
template<int MPX>
__global__ __launch_bounds__(256) void k_oproj(const unsigned short* __restrict__ A,
                                               const unsigned short* __restrict__ W,
                                               const float* __restrict__ bias,
                                               float* __restrict__ out){
  __shared__ unsigned short As[128*32];
  __shared__ unsigned short Bs[128*32];
  const int id = blockIdx.x, xcd = id & 7, j = id >> 3;
  const int m0 = (xcd*MPX + j/4) * 128;
  const int n0 = (j & 3) * 128;
  const int t = threadIdx.x, l = t&63, w = t>>6;
  const int wm = w>>1, wn = w&1;
  f32x4 acc[4][4] = {};
  const char* Ab = (const char*)A + (size_t)m0*1024;
  const char* Wb = (const char*)W + (size_t)n0*1024;
  char* AsB = (char*)As; char* BsB = (char*)Bs;
  const int lofs = w*1024;
  const int grow = w*16 + (l>>2);
  const int gcol = (l&3)*16;

  for (int kt=0; kt<16; ++kt){
    __syncthreads();
    const int kb = kt*64;
    for (int i=0;i<2;++i){
      gload16(Ab + (size_t)(i*64 + grow)*1024 + kb + gcol, AsB + i*4096 + lofs);
      gload16(Wb + (size_t)(i*64 + grow)*1024 + kb + gcol, BsB + i*4096 + lofs);
    }
    __syncthreads();
    bf16x8 a[4], b[4];
    for (int i=0;i<4;++i){
      a[i] = *(const bf16x8*)(AsB + (wm*64 + i*16 + (l&15))*64 + (l>>4)*16);
      b[i] = *(const bf16x8*)(BsB + (wn*64 + i*16 + (l&15))*64 + (l>>4)*16);
    }
    for (int i=0;i<4;++i)
      for (int jj=0;jj<4;++jj)
        acc[i][jj] = mfma16(a[i], b[jj], acc[i][jj]);
  }
  for (int i=0;i<4;++i)
    for (int jj=0;jj<4;++jj){
      const int nn = n0 + wn*64 + jj*16 + (l&15);
      const float bv = bias[nn];
      for (int r=0;r<4;++r){
        const int mm = m0 + wm*64 + i*16 + (l>>4)*4 + r;
        out[ (size_t)mm*512 + nn ] = acc[i][jj][r] + bv;
      }
    }
}

// ---------------- single-pass QK^T + exp + rowsum; spills bf16 expS ----------------
__global__ __launch_bounds__(256) void k_qks(const unsigned short* __restrict__ Dm,
                                             const unsigned short* __restrict__ Pm,
                                             unsigned short* __restrict__ expS,
                                             float* __restrict__ rinv){
  __shared__ unsigned short Ds[128*128];
  __shared__ unsigned short Ps[128*128];
  const int id = blockIdx.x, xcd = id & 7, j = id >> 3;
  const int bh = xcd*32 + (j>>1), qt = j&1;
  const int t = threadIdx.x, l = t&63, w = t>>6;
  char* DsB = (char*)Ds; char* PsB = (char*)Ps;
  const char* dsrc = (const char*)Dm + ((size_t)bh*256 + qt*128)*256;
  const char* psrc = (const char*)Pm + (size_t)bh*1024*256;
  char* egbase = (char*)expS + ((size_t)bh*256 + qt*128)*2048;
  const int lofs = w*1024;

  for (int i=0;i<8;++i)
    gload16(dsrc + i*4096 + lofs + l*16, DsB + i*4096 + lofs);

  float rs[2][4] = {};
  for (int pt=0; pt<8; ++pt){
    __syncthreads();            // prev copy done / Ps free
    for (int i=0;i<8;++i)
      gload16(psrc + pt*32768 + i*4096 + lofs + l*16, PsB + i*4096 + lofs);
    __syncthreads();            // Ps (and Ds) resident
    f32x4 acc[2][8] = {};
    for (int kt=0;kt<4;++kt){
      bf16x8 a[2];
      for (int fm=0;fm<2;++fm){
        const int row = w*32 + fm*16 + (l&15);
        const int byteo = (kt*64 + (l>>4)*16) ^ ((row&15)<<4);
        a[fm] = *(const bf16x8*)(DsB + row*256 + byteo);
      }
      for (int fn=0;fn<8;++fn){
        const int row = fn*16 + (l&15);
        const int byteo = (kt*64 + (l>>4)*16) ^ ((row&15)<<4);
        bf16x8 b = *(const bf16x8*)(PsB + row*256 + byteo);
        acc[0][fn] = mfma16(a[0], b, acc[0][fn]);
        acc[1][fn] = mfma16(a[1], b, acc[1][fn]);
      }
    }
    __syncthreads();            // done reading Ps -> reuse as exp staging
    for (int fm=0;fm<2;++fm)
      for (int fn=0;fn<8;++fn)
        for (int r=0;r<4;++r){
          float e = __expf(acc[fm][fn][r]);
          rs[fm][r] += e;
          const int q = w*32 + fm*16 + (l>>4)*4 + r;
          const int p = fn*16 + (l&15);
          *(unsigned short*)(PsB + q*256 + ((p*2) ^ ((q&15)<<4))) = f2bf(e);
        }
    __syncthreads();            // exp tile complete
    for (int i=0;i<4;++i){
      const int idx = i*256 + t;
      const int row = idx>>3, colb = (idx&7)*32;
      int4 v0 = *(const int4*)(PsB + row*256 + colb);
      int4 v1 = *(const int4*)(PsB + row*256 + colb + 16);
      char* gp = egbase + (size_t)row*2048 + pt*256 + colb;
      *(int4*)gp = v0;
      *(int4*)(gp+16) = v1;
    }
  }
  for (int m=1;m<16;m<<=1)
    for (int fm=0;fm<2;++fm)
      for (int r=0;r<4;++r)
        rs[fm][r] += __shfl_xor(rs[fm][r], m, 64);
  if ((l&15)==0){
    for (int fm=0;fm<2;++fm)
      for (int r=0;r<4;++r){
        const int row = w*32 + fm*16 + (l>>4)*4 + r;
        rinv[ (size_t)bh*256 + qt*128 + row ] = 1.f/rs[fm][r];
      }
  }
}

// ---------------- fused normalize-write-attn + ctx_d = P@Vp ----------------
__global__ __launch_bounds__(256) void k_nctxd(const unsigned short* __restrict__ expS,
                                               const unsigned short* __restrict__ Vpt,
                                               const float* __restrict__ rinv,
                                               float* __restrict__ attn,
                                               unsigned short* __restrict__ Cd){
  __shared__ unsigned short Es[128*128];
  __shared__ unsigned short Vs[64*128];
  __shared__ float ri[128];
  const int id = blockIdx.x, xcd = id & 7, j = id >> 3;
  const int bh = xcd*32 + (j>>1), qt = j&1;
  const int b = bh>>3, h = bh&7;
  const int t = threadIdx.x, l = t&63, w = t>>6;
  char* EsB = (char*)Es; char* VsB = (char*)Vs;
  if (t < 128) ri[t] = rinv[ (size_t)bh*256 + qt*128 + t ];
  const char* esrc = (const char*)expS + ((size_t)bh*256 + qt*128)*2048;
  const char* vsrc = (const char*)Vpt + (size_t)bh*64*2048;
  const int lofs = w*1024;
  f32x4 accd[2][4] = {};

  for (int pt=0; pt<8; ++pt){
    __syncthreads();
    for (int i=0;i<8;++i){
      const int ib = i*4096 + lofs + l*16;
      gload16(esrc + (size_t)(ib>>8)*2048 + pt*256 + (ib&255), EsB + i*4096 + lofs);
    }
    for (int i=0;i<4;++i){
      const int ib = i*4096 + lofs + l*16;
      gload16(vsrc + (size_t)(ib>>8)*2048 + pt*256 + (ib&255), VsB + i*4096 + lofs);
    }
    __syncthreads();
    for (int kt=0;kt<4;++kt){
      bf16x8 a[2], bb[4];
      for (int fm=0;fm<2;++fm){
        const int row = w*32 + fm*16 + (l&15);
        const int byteo = (kt*64 + (l>>4)*16) ^ ((row&15)<<4);
        a[fm] = *(const bf16x8*)(EsB + row*256 + byteo);
      }
      for (int fn=0;fn<4;++fn){
        const int row = fn*16 + (l&15);
        const int byteo = (kt*64 + (l>>4)*16) ^ ((row&15)<<4);
        bb[fn] = *(const bf16x8*)(VsB + row*256 + byteo);
      }
      for (int fm=0;fm<2;++fm)
        for (int fn=0;fn<4;++fn)
          accd[fm][fn] = mfma16(a[fm], bb[fn], accd[fm][fn]);
      // normalized attn write from the A-fragments
      for (int fm=0;fm<2;++fm){
        const int row = w*32 + fm*16 + (l&15);
        const float rv = ri[row];
        float f[8];
        for (int jj=0;jj<8;++jj) f[jj] = bf2f((unsigned short)a[fm][jj]) * rv;
        float4 lo = {f[0],f[1],f[2],f[3]};
        float4 hi = {f[4],f[5],f[6],f[7]};
        float* op = attn + ((size_t)bh*256 + qt*128 + row)*1024 + pt*128 + kt*32 + (l>>4)*8;
        *(float4*)op = lo;
        *(float4*)(op+4) = hi;
      }
    }
  }
  for (int fm=0;fm<2;++fm)
    for (int fn=0;fn<4;++fn)
      for (int r=0;r<4;++r){
        const int row = w*32 + fm*16 + (l>>4)*4 + r;
        const float v = accd[fm][fn][r] * ri[row];
        const int col = fn*16 + (l&15);
        Cd[ ((size_t)b*256 + qt*128 + row)*512 + h*64 + col ] = f2bf(v);
      }
}

// ---------------- ctx_p = expS^T @ (rinv*Vd) ----------------
__global__ __launch_bounds__(256) void k_ctxp(const unsigned short* __restrict__ expS,
                                              const unsigned short* __restrict__ Vdt,
                                              const float* __restrict__ rinv,
                                              unsigned short* __restrict__ Cp){
  __shared__ unsigned short As[128*40];
  __shared__ unsigned short Bs[64*40];
  __shared__ float ri[256];
  const int id = blockIdx.x, xcd = id & 7, j = id >> 3;
  const int bh = xcd*32 + (j>>3), mt = j&7;
  const int b = bh>>3, h = bh&7;
  const int t = threadIdx.x, l = t&63, w = t>>6;
  ri[t] = rinv[ (size_t)bh*256 + t ];
  const char* ebase = (const char*)expS + (size_t)bh*256*2048;
  const unsigned short* vbase = Vdt + (size_t)bh*16384;
  f32x4 acc[2][4] = {};
  for (int kt=0; kt<8; ++kt){
    __syncthreads();
    for (int i=0;i<4;++i){
      const int idx = i*256 + t;
      const int ql = idx>>5, p4 = idx&31;
      const int qg = kt*32 + ql;
      ushort4 v = *(const ushort4*)(ebase + (size_t)qg*2048 + ((mt*256 + p4*8) ^ ((qg&15)<<4)));
      As[(p4*4+0)*40 + ql] = v.x;
      As[(p4*4+1)*40 + ql] = v.y;
      As[(p4*4+2)*40 + ql] = v.z;
      As[(p4*4+3)*40 + ql] = v.w;
    }
    for (int i=0;i<2;++i){
      const int idx = i*256 + t;
      const int row = idx>>3, c4 = idx&7;
      ushort4 vv = *(const ushort4*)(vbase + (size_t)row*256 + kt*32 + c4*4);
      const float* rp = &ri[kt*32 + c4*4];
      Bs[row*40 + c4*4+0] = f2bf(bf2f(vv.x) * rp[0]);
      Bs[row*40 + c4*4+1] = f2bf(bf2f(vv.y) * rp[1]);
      Bs[row*40 + c4*4+2] = f2bf(bf2f(vv.z) * rp[2]);
      Bs[row*40 + c4*4+3] = f2bf(bf2f(vv.w) * rp[3]);
    }
    __syncthreads();
    bf16x8 a[2], bb[4];
    for (int fm=0;fm<2;++fm)
      a[fm] = *(const bf16x8*)(As + (w*32 + fm*16 + (l&15))*40 + (l>>4)*8);
    for (int fn=0;fn<4;++fn)
      bb[fn] = *(const bf16x8*)(Bs + (fn*16 + (l&15))*40 + (l>>4)*8);
    for (int fm=0;fm<2;++fm)
      for (int fn=0;fn<4;++fn)
        acc[fm][fn] = mfma16(a[fm], bb[fn], acc[fm][fn]);
  }
  for (int fm=0;fm<2;++fm)
    for (int fn=0;fn<4;++fn)
      for (int r=0;r<4;++r){
        const int row = mt*128 + w*32 + fm*16 + (l>>4)*4 + r;
        const int col = fn*16 + (l&15);
        Cp[ ((size_t)b*1024 + row)*512 + h*64 + col ] = f2bf(acc[fm][fn][r]);
      }
}

extern "C" void kernel_launch(void* const* d_in, const int* in_sizes, int n_in,
                              void* d_out, int out_size, void* d_ws, size_t ws_size,
                              hipStream_t stream){
  const float* drug    = (const float*)d_in[0];
  const float* protein = (const float*)d_in[1];
  const float* Wqd=(const float*)d_in[2];  const float* bqd=(const float*)d_in[3];
  const float* Wkp=(const float*)d_in[4];  const float* bkp=(const float*)d_in[5];
  const float* Wvp=(const float*)d_in[6];  const float* bvp=(const float*)d_in[7];
  const float* Wqp=(const float*)d_in[8];  const float* bqp=(const float*)d_in[9];
  const float* Wkd=(const float*)d_in[10]; const float* bkd=(const float*)d_in[11];
  const float* Wvd=(const float*)d_in[12]; const float* bvd=(const float*)d_in[13];
  const float* alpha=(const float*)d_in[14];
  const float* Wod=(const float*)d_in[15]; const float* bod=(const float*)d_in[16];
  const float* Wop=(const float*)d_in[17]; const float* bop=(const float*)d_in[18];

  char* ws = (char*)d_ws;
  // layout (bytes): expS 0..128M overlays Xd/Xp (dead before k_qks writes)
  unsigned short* expS = (unsigned short*)(ws + 0);          // [bh][256][1024] bf16, p-swizzled
  unsigned short* Xd   = (unsigned short*)(ws + 0);          // 8192x512 bf16  (dead after proj)
  unsigned short* Xp   = (unsigned short*)(ws + 8388608);    // 32768x512 bf16 (dead after proj)
  unsigned short* Wb   = (unsigned short*)(ws + 134217728);  // 8 x 512x512 bf16
  unsigned short* Dm   = (unsigned short*)(ws + 138412032);  // [bh][256][128] swizzled (dead after qks)
  unsigned short* Cd   = (unsigned short*)(ws + 138412032);  // overlay
  unsigned short* Pm   = (unsigned short*)(ws + 155189248);  // [bh][1024][128] swizzled (dead after qks)
  unsigned short* Cp   = (unsigned short*)(ws + 155189248);  // overlay
  unsigned short* Vpt  = (unsigned short*)(ws + 222298112);  // [bh][64][1024] swizzled
  unsigned short* Vdt  = (unsigned short*)(ws + 255852544);  // [bh][64][256] linear
  float*          rinv = (float*)         (ws + 264241152);  // [bh][256]

  float* attn = (float*)d_out;
  float* outd = (float*)d_out + 67108864;
  float* outp = (float*)d_out + 71303168;

  // conversions
  k_cvt<<<4096, 256, 0, stream>>>(drug,    Xd, 1048576);
  k_cvt<<<16384,256, 0, stream>>>(protein, Xp, 4194304);
  W8 wlist = {{Wqd, Wkd, Wvd, Wkp, Wqp, Wvp, Wod, Wop}};
  k_cvtw<<<2048, 256, 0, stream>>>(wlist, Wb);

  // fused projections
  k_proj<0><<<768,  256, 0, stream>>>(Xd, Wb + 0*262144, bqd, bkd, bvd, Dm, Vdt, alpha);
  k_proj<1><<<3072, 256, 0, stream>>>(Xp, Wb + 3*262144, bkp, bqp, bvp, Pm, Vpt, alpha);

  // attention: single pass, spill bf16 expS + rinv
  k_qks<<<512, 256, 0, stream>>>(Dm, Pm, expS, rinv);

  // normalize + write f32 attn + ctx_d
  k_nctxd<<<512, 256, 0, stream>>>(expS, Vpt, rinv, attn, Cd);

  // ctx_p
  k_ctxp<<<2048, 256, 0, stream>>>(expS, Vdt, rinv, Cp);

  // output projections
  k_oproj<8> <<<256,  256, 0, stream>>>(Cd, Wb + 6*262144, bod, outd);
  k_oproj<32><<<1024, 256, 0, stream>>>(Cp, Wb + 7*262144, bop, outp);
}